// Round 1
// baseline (4815.485 us; speedup 1.0000x reference)
//
#include <hip/hip_runtime.h>
#include <math.h>

#define B_ 4
#define C_ 512
#define T_ 16
#define HW_ 784
#define CO_ 32
#define TT_ 48     // 3*T
#define T2_ 32     // 2*T
#define TEMP_ 4.0f

#define PTILE 64
#define KC 16
#define NCHUNK 49   // 784/16
#define PBLK 13     // ceil(784/64)

// ---------------------------------------------------------------------------
// K1: per-position projection with one 32x512 weight matrix (staged in LDS).
// mode 0: semantic -> L2-normalize over the 32 outputs -> dst (x_norm);
//         also copies x into the center output time slots (3t+1).
// mode 1: raw projection -> dst (xa).
// grid: 196 blocks * 256 threads = 50176 = B*T*HW positions exactly.
// ---------------------------------------------------------------------------
__global__ __launch_bounds__(256) void proj_kernel(
    const float* __restrict__ x, const float* __restrict__ Wmat,
    float* __restrict__ out, float* __restrict__ dst, int mode)
{
    __shared__ float Wl[CO_ * C_];   // 64 KB
    const int tid = threadIdx.x;
    for (int i = tid; i < CO_ * C_; i += 256) Wl[i] = Wmat[i];
    __syncthreads();

    const int gid = blockIdx.x * 256 + tid;        // [0, 50176)
    const int b = gid / (T_ * HW_);
    const int r = gid % (T_ * HW_);
    const int t = r / HW_;
    const int p = r % HW_;

    const float* xp = x + ((size_t)b * C_ * T_ + t) * HW_ + p;
    float* outc = out + ((size_t)b * C_ * TT_ + 3 * t + 1) * HW_ + p;

    float acc[CO_];
    #pragma unroll
    for (int o = 0; o < CO_; ++o) acc[o] = 0.f;

    for (int c = 0; c < C_; ++c) {
        float xv = xp[(size_t)c * (T_ * HW_)];
        if (mode == 0) outc[(size_t)c * (TT_ * HW_)] = xv;   // center copy
        #pragma unroll
        for (int o = 0; o < CO_; ++o) acc[o] += Wl[o * C_ + c] * xv;
    }

    float* d = dst + (size_t)gid * CO_;
    if (mode == 0) {
        float s = 0.f;
        #pragma unroll
        for (int o = 0; o < CO_; ++o) s += acc[o] * acc[o];
        float sc = 1.f / fmaxf(sqrtf(s), 1e-12f);
        #pragma unroll
        for (int o = 0; o < CO_; ++o) d[o] = acc[o] * sc;
    } else {
        #pragma unroll
        for (int o = 0; o < CO_; ++o) d[o] = acc[o];
    }
}

// ---------------------------------------------------------------------------
// K2: neighbor attention with online softmax, writes UNGATED neighbor values
// into their final interleaved output slots (tt = 3t + 2n).
// Block = (b, t, n, 64-query tile); thread owns 4 queries x 32 channels.
// Out-of-range neighbor frames -> write zeros (matches zero-padded reference).
// ---------------------------------------------------------------------------
__global__ __launch_bounds__(256) void attn_kernel(
    const float* __restrict__ x, const float* __restrict__ xnorm,
    float* __restrict__ out)
{
    __shared__ __align__(16) float Vs[C_][20];      // V chunk, [c][q], pad 16->20
    __shared__ __align__(16) float Ks[KC][36];      // K chunk, [q][o]
    __shared__ __align__(16) float Qs[PTILE][36];   // Q tile,  [p][o]
    __shared__ __align__(16) float Ps[PTILE][20];   // probs,   [p][q]

    const int tid = threadIdx.x;
    const int blk = blockIdx.x;
    const int pblk = blk % PBLK;
    const int slice = blk / PBLK;          // b*32 + t*2 + n
    const int n = slice & 1;
    const int t = (slice >> 1) & (T_ - 1);
    const int b = slice >> 5;
    const int tn = t + (n ? 1 : -1);
    const int tt = 3 * t + 2 * n;
    const int p0 = pblk * PTILE;

    float* outb = out + (size_t)b * C_ * TT_ * HW_ + (size_t)tt * HW_;

    if (tn < 0 || tn >= T_) {              // zero-padded boundary frame
        for (int i = tid; i < C_ * PTILE; i += 256) {
            int c = i >> 6, pl = i & (PTILE - 1);
            int p = p0 + pl;
            if (p < HW_) outb[(size_t)c * (TT_ * HW_) + p] = 0.f;
        }
        return;
    }

    const float* qbase = xnorm + (size_t)(b * T_ + t) * HW_ * CO_;
    const float* kbase = xnorm + (size_t)(b * T_ + tn) * HW_ * CO_;
    const float* vbase = x + (size_t)b * C_ * T_ * HW_ + (size_t)tn * HW_;

    for (int i = tid; i < PTILE * CO_; i += 256) {
        int pl = i >> 5, o = i & 31;
        int p = p0 + pl;
        Qs[pl][o] = (p < HW_) ? qbase[(size_t)p * CO_ + o] : 0.f;
    }

    const int pg = tid >> 4;   // query group 0..15 (owns p = pg*4 + pp)
    const int cg = tid & 15;   // channel group / key lane

    float O[4][32];
    float m[4], l[4];
    #pragma unroll
    for (int pp = 0; pp < 4; ++pp) {
        m[pp] = -1e30f; l[pp] = 0.f;
        #pragma unroll
        for (int j = 0; j < 32; ++j) O[pp][j] = 0.f;
    }

    for (int ch = 0; ch < NCHUNK; ++ch) {
        const int q0 = ch * KC;
        // stage K chunk (16 keys x 32 dims)
        for (int i = tid; i < KC * CO_; i += 256) {
            int ql = i >> 5, o = i & 31;
            Ks[ql][o] = kbase[(size_t)(q0 + ql) * CO_ + o];
        }
        // stage V chunk (512 channels x 16 keys), float4 rows
        for (int i = tid; i < C_ * 4; i += 256) {
            int c = i >> 2, q4 = i & 3;
            const float4 v = *reinterpret_cast<const float4*>(
                vbase + (size_t)c * (T_ * HW_) + q0 + q4 * 4);
            *reinterpret_cast<float4*>(&Vs[c][q4 * 4]) = v;
        }
        __syncthreads();

        // scores: thread (pg, ql=cg) -> 4 queries x 1 key
        float4 kr[8];
        {
            const float4* kv = reinterpret_cast<const float4*>(&Ks[cg][0]);
            #pragma unroll
            for (int u = 0; u < 8; ++u) kr[u] = kv[u];
        }
        float scv[4];
        #pragma unroll
        for (int pp = 0; pp < 4; ++pp) {
            const float4* qv = reinterpret_cast<const float4*>(&Qs[pg * 4 + pp][0]);
            float s = 0.f;
            #pragma unroll
            for (int u = 0; u < 8; ++u) {
                float4 a = qv[u];
                s += a.x * kr[u].x + a.y * kr[u].y + a.z * kr[u].z + a.w * kr[u].w;
            }
            scv[pp] = s * TEMP_;
        }

        // online softmax per query row (16 key-lanes per row, shfl butterfly)
        float al[4];
        #pragma unroll
        for (int pp = 0; pp < 4; ++pp) {
            float mc = scv[pp];
            mc = fmaxf(mc, __shfl_xor(mc, 1, 16));
            mc = fmaxf(mc, __shfl_xor(mc, 2, 16));
            mc = fmaxf(mc, __shfl_xor(mc, 4, 16));
            mc = fmaxf(mc, __shfl_xor(mc, 8, 16));
            float mn = fmaxf(m[pp], mc);
            float a  = __expf(m[pp] - mn);
            float pv = __expf(scv[pp] - mn);
            float ls = pv;
            ls += __shfl_xor(ls, 1, 16);
            ls += __shfl_xor(ls, 2, 16);
            ls += __shfl_xor(ls, 4, 16);
            ls += __shfl_xor(ls, 8, 16);
            l[pp] = l[pp] * a + ls;
            m[pp] = mn;
            al[pp] = a;
            Ps[pg * 4 + pp][cg] = pv;
        }
        __syncthreads();

        // rescale accumulators
        #pragma unroll
        for (int pp = 0; pp < 4; ++pp)
            #pragma unroll
            for (int j = 0; j < 32; ++j) O[pp][j] *= al[pp];

        // PV: O[pp][j] += sum_q P[p][q] * V[q][c],  c = cg + 16*j
        #pragma unroll
        for (int qg = 0; qg < 4; ++qg) {
            float4 ps[4];
            #pragma unroll
            for (int pp = 0; pp < 4; ++pp)
                ps[pp] = *reinterpret_cast<const float4*>(&Ps[pg * 4 + pp][qg * 4]);
            #pragma unroll
            for (int j = 0; j < 32; ++j) {
                const float4 v = *reinterpret_cast<const float4*>(&Vs[cg + 16 * j][qg * 4]);
                #pragma unroll
                for (int pp = 0; pp < 4; ++pp) {
                    O[pp][j] += ps[pp].x * v.x + ps[pp].y * v.y
                              + ps[pp].z * v.z + ps[pp].w * v.w;
                }
            }
        }
        __syncthreads();
    }

    // epilogue: normalize by l, write ungated neighbor values
    #pragma unroll
    for (int pp = 0; pp < 4; ++pp) {
        int p = p0 + pg * 4 + pp;
        if (p >= HW_) continue;
        float rl = 1.f / l[pp];
        #pragma unroll
        for (int j = 0; j < 32; ++j) {
            int c = cg + 16 * j;
            outb[(size_t)c * (TT_ * HW_) + p] = O[pp][j] * rl;
        }
    }
}

// ---------------------------------------------------------------------------
// K3: gating. For each neighbor output column (b, tt, p): na = Wn . vec,
// g = sigmoid(sum_o Watt[o]*xa[o]*na[o]), scale column in place.
// grid: 392 * 256 = 100352 = B * 2T * HW exactly. Boundary zeros stay zero.
// ---------------------------------------------------------------------------
__global__ __launch_bounds__(256) void gate_kernel(
    const float* __restrict__ Wn, const float* __restrict__ Watt,
    const float* __restrict__ xa, float* __restrict__ out)
{
    __shared__ float Wl[CO_ * C_];   // 64 KB
    const int tid = threadIdx.x;
    for (int i = tid; i < CO_ * C_; i += 256) Wl[i] = Wn[i];
    __syncthreads();

    const int gid = blockIdx.x * 256 + tid;     // [0, 100352)
    const int b = gid / (T2_ * HW_);
    const int r = gid % (T2_ * HW_);
    const int t2 = r / HW_;
    const int p = r % HW_;
    const int t = t2 >> 1, n = t2 & 1;
    const int tt = 3 * t + 2 * n;

    float* op = out + (size_t)b * C_ * TT_ * HW_ + (size_t)tt * HW_ + p;

    float na[CO_];
    #pragma unroll
    for (int o = 0; o < CO_; ++o) na[o] = 0.f;
    for (int c = 0; c < C_; ++c) {
        float v = op[(size_t)c * (TT_ * HW_)];
        #pragma unroll
        for (int o = 0; o < CO_; ++o) na[o] += Wl[o * C_ + c] * v;
    }

    const float* xab = xa + ((size_t)(b * T_ + t) * HW_ + p) * CO_;
    float g = 0.f;
    #pragma unroll
    for (int o = 0; o < CO_; ++o) g += Watt[o] * xab[o] * na[o];
    g = 1.f / (1.f + __expf(-g));

    for (int c = 0; c < C_; ++c) op[(size_t)c * (TT_ * HW_)] *= g;
}

extern "C" void kernel_launch(void* const* d_in, const int* in_sizes, int n_in,
                              void* d_out, int out_size, void* d_ws, size_t ws_size,
                              hipStream_t stream) {
    const float* x    = (const float*)d_in[0];
    const float* Ws   = (const float*)d_in[1];
    const float* Wx   = (const float*)d_in[2];
    const float* Wn   = (const float*)d_in[3];
    const float* Watt = (const float*)d_in[4];
    float* out = (float*)d_out;

    float* xnorm = (float*)d_ws;                                 // B*T*HW*CO floats
    float* xa    = xnorm + (size_t)B_ * T_ * HW_ * CO_;          // B*T*HW*CO floats

    proj_kernel<<<dim3(196), dim3(256), 0, stream>>>(x, Ws, out, xnorm, 0);
    proj_kernel<<<dim3(196), dim3(256), 0, stream>>>(x, Wx, out, xa, 1);
    attn_kernel<<<dim3(1664), dim3(256), 0, stream>>>(x, xnorm, out);
    gate_kernel<<<dim3(392), dim3(256), 0, stream>>>(Wn, Watt, xa, out);
}

// Round 2
// 1364.312 us; speedup vs baseline: 3.5296x; 3.5296x over previous
//
#include <hip/hip_runtime.h>
#include <math.h>

#define B_ 4
#define C_ 512
#define T_ 16
#define HW_ 784
#define CO_ 32
#define TT_ 48     // 3*T
#define T2_ 32     // 2*T
#define TEMP_ 4.0f

#define NCH 25      // ceil(784/32) key chunks of 32
#define PBLK 13     // ceil(784/64) query tiles of 64

typedef __attribute__((ext_vector_type(8))) short bf16x8;
typedef __attribute__((ext_vector_type(4))) float f32x4;

__device__ __forceinline__ ushort f2bf(float f) {
    union { float f; unsigned u; } v; v.f = f;
    unsigned r = v.u + 0x7fffu + ((v.u >> 16) & 1u);   // RNE
    return (ushort)(r >> 16);
}

// ---------------------------------------------------------------------------
// K0: x fp32 -> bf16 copy (same [b][c][t][hw] layout). 8 elems/thread.
// grid: 12544 * 256 threads = 3,211,264 -> 25,690,112 elems exactly.
// ---------------------------------------------------------------------------
__global__ __launch_bounds__(256) void convert_kernel(
    const float4* __restrict__ x, uint4* __restrict__ xb)
{
    const int gid = blockIdx.x * 256 + threadIdx.x;
    float4 a = x[(size_t)gid * 2];
    float4 b = x[(size_t)gid * 2 + 1];
    ushort r[8] = { f2bf(a.x), f2bf(a.y), f2bf(a.z), f2bf(a.w),
                    f2bf(b.x), f2bf(b.y), f2bf(b.z), f2bf(b.w) };
    xb[gid] = *reinterpret_cast<const uint4*>(r);
}

// ---------------------------------------------------------------------------
// K1: per-position projection, W (32x512) staged in LDS.
// mode 0: semantic -> L2-normalize -> xnorm (bf16, [pos][32]); also copies x
//         into the center output time slots (3t+1).
// mode 1: raw projection -> xa (fp32, [pos][32]).
// grid: 196 * 256 = 50176 = B*T*HW positions.
// ---------------------------------------------------------------------------
__global__ __launch_bounds__(256) void proj_kernel(
    const float* __restrict__ x, const float* __restrict__ Wmat,
    float* __restrict__ out, ushort* __restrict__ dstb, float* __restrict__ dstf,
    int mode)
{
    __shared__ float Wl[CO_ * C_];   // 64 KB
    const int tid = threadIdx.x;
    for (int i = tid; i < CO_ * C_; i += 256) Wl[i] = Wmat[i];
    __syncthreads();

    const int gid = blockIdx.x * 256 + tid;        // [0, 50176)
    const int b = gid / (T_ * HW_);
    const int r = gid % (T_ * HW_);
    const int t = r / HW_;
    const int p = r % HW_;

    const float* xp = x + ((size_t)b * C_ * T_ + t) * HW_ + p;
    float* outc = out + ((size_t)b * C_ * TT_ + 3 * t + 1) * HW_ + p;

    float acc[CO_];
    #pragma unroll
    for (int o = 0; o < CO_; ++o) acc[o] = 0.f;

    for (int c = 0; c < C_; ++c) {
        float xv = xp[(size_t)c * (T_ * HW_)];
        if (mode == 0) outc[(size_t)c * (TT_ * HW_)] = xv;   // center copy
        #pragma unroll
        for (int o = 0; o < CO_; ++o) acc[o] += Wl[o * C_ + c] * xv;
    }

    if (mode == 0) {
        float s = 0.f;
        #pragma unroll
        for (int o = 0; o < CO_; ++o) s += acc[o] * acc[o];
        float sc = 1.f / fmaxf(sqrtf(s), 1e-12f);
        ushort tmp[CO_];
        #pragma unroll
        for (int o = 0; o < CO_; ++o) tmp[o] = f2bf(acc[o] * sc);
        uint4* dp = reinterpret_cast<uint4*>(dstb + (size_t)gid * CO_);
        #pragma unroll
        for (int j = 0; j < 4; ++j) dp[j] = reinterpret_cast<const uint4*>(tmp)[j];
    } else {
        float* d = dstf + (size_t)gid * CO_;
        #pragma unroll
        for (int o = 0; o < CO_; ++o) d[o] = acc[o];
    }
}

// ---------------------------------------------------------------------------
// K2: MFMA flash attention (two-pass, no accumulator rescale).
// Block = (slice = b*32+t*2+n, 64-query tile). 4 waves; wave w owns
//   pass A/B softmax rows [w*16, w*16+16) and PV channel stripe [w*128, ...).
// Pass A: QK^T (16x16x32 bf16 MFMA) -> per-row max m and denom l.
// Pass B: recompute S, P = exp(s-m)/l in bf16 -> LDS (layout transpose),
//         O += P @ V with V B-frags loaded straight from global bf16 x.
// Boundary frames (t=0 prev / t=15 next) -> zero-fill (matches zero-pad ref).
// ---------------------------------------------------------------------------
__global__ __launch_bounds__(256, 2) void attn_mfma(
    const ushort* __restrict__ xnorm, const ushort* __restrict__ xbf,
    float* __restrict__ out)
{
    __shared__ ushort Pbuf[2][64][40];   // P tiles, row stride 40 (80B = 20 banks)
    __shared__ float mrow_s[64], lrow_s[64];

    const int tid  = threadIdx.x;
    const int w    = tid >> 6;
    const int lane = tid & 63;
    const int l15  = lane & 15;
    const int quad = lane >> 4;

    const int blk   = blockIdx.x;
    const int pblk  = blk % PBLK;
    const int slice = blk / PBLK;
    const int n = slice & 1;
    const int t = (slice >> 1) & (T_ - 1);
    const int b = slice >> 5;
    const int tn = t + (n ? 1 : -1);
    const int tt = 3 * t + 2 * n;
    const int p0 = pblk * 64;

    float* outb = out + (size_t)b * C_ * TT_ * HW_ + (size_t)tt * HW_;

    if (tn < 0 || tn >= T_) {            // zero-padded boundary frame
        for (int i = tid; i < C_ * 16; i += 256) {
            int c = i >> 4, p = p0 + (i & 15) * 4;
            if (p < HW_) {
                float4 z = {0.f, 0.f, 0.f, 0.f};
                *reinterpret_cast<float4*>(outb + (size_t)c * (TT_ * HW_) + p) = z;
            }
        }
        return;
    }

    const ushort* qb = xnorm + (size_t)(b * T_ + t) * HW_ * CO_;
    const ushort* kb = xnorm + (size_t)(b * T_ + tn) * HW_ * CO_;
    const ushort* vb = xbf + ((size_t)b * C_ * T_ + tn) * HW_;

    // Q A-fragment for this wave's M-tile (constant across chunks & passes)
    const int qp = p0 + w * 16 + l15;
    const int qpc = qp < HW_ ? qp : HW_ - 1;
    const bf16x8 Aq = *reinterpret_cast<const bf16x8*>(qb + (size_t)qpc * CO_ + quad * 8);

    const f32x4 zf = {0.f, 0.f, 0.f, 0.f};

    // ---------------- pass A: row stats ----------------
    float m_run[4], l_run[4];
    #pragma unroll
    for (int r = 0; r < 4; ++r) { m_run[r] = -1e30f; l_run[r] = 0.f; }

    for (int ch = 0; ch < NCH; ++ch) {
        const int q0 = ch * 32;
        int k0 = q0 + l15;        int k0c = k0 < HW_ ? k0 : HW_ - 1;
        int k1 = q0 + 16 + l15;   int k1c = k1 < HW_ ? k1 : HW_ - 1;
        bf16x8 Bk0 = *reinterpret_cast<const bf16x8*>(kb + (size_t)k0c * CO_ + quad * 8);
        bf16x8 Bk1 = *reinterpret_cast<const bf16x8*>(kb + (size_t)k1c * CO_ + quad * 8);
        f32x4 S0 = __builtin_amdgcn_mfma_f32_16x16x32_bf16(Aq, Bk0, zf, 0, 0, 0);
        f32x4 S1 = __builtin_amdgcn_mfma_f32_16x16x32_bf16(Aq, Bk1, zf, 0, 0, 0);
        const bool v0 = k0 < HW_, v1 = k1 < HW_;
        #pragma unroll
        for (int r = 0; r < 4; ++r) {
            float s0 = v0 ? S0[r] * TEMP_ : -1e30f;
            float s1 = v1 ? S1[r] * TEMP_ : -1e30f;
            float mn = fmaxf(m_run[r], fmaxf(s0, s1));
            l_run[r] = l_run[r] * __expf(m_run[r] - mn) + __expf(s0 - mn) + __expf(s1 - mn);
            m_run[r] = mn;
        }
    }
    #pragma unroll
    for (int r = 0; r < 4; ++r) {
        float m_ = m_run[r], l_ = l_run[r];
        #pragma unroll
        for (int d = 1; d < 16; d <<= 1) {
            float mo = __shfl_xor(m_, d);
            float lo = __shfl_xor(l_, d);
            float mn = fmaxf(m_, mo);
            l_ = l_ * __expf(m_ - mn) + lo * __expf(mo - mn);
            m_ = mn;
        }
        if (l15 == 0) {
            int row = w * 16 + quad * 4 + r;
            mrow_s[row] = m_;
            lrow_s[row] = 1.f / l_;
        }
    }
    __syncthreads();

    float mrw[4], lirw[4];
    #pragma unroll
    for (int r = 0; r < 4; ++r) {
        mrw[r]  = mrow_s[w * 16 + quad * 4 + r];
        lirw[r] = lrow_s[w * 16 + quad * 4 + r];
    }

    // ---------------- pass B: P build + PV ----------------
    const int c0 = w * 128;
    f32x4 acc[4][8];
    #pragma unroll
    for (int mt = 0; mt < 4; ++mt)
        #pragma unroll
        for (int nt = 0; nt < 8; ++nt) acc[mt][nt] = zf;

    for (int ch = 0; ch < NCH; ++ch) {
        const int q0 = ch * 32;
        const int buf = ch & 1;
        {
            int k0 = q0 + l15;        int k0c = k0 < HW_ ? k0 : HW_ - 1;
            int k1 = q0 + 16 + l15;   int k1c = k1 < HW_ ? k1 : HW_ - 1;
            bf16x8 Bk0 = *reinterpret_cast<const bf16x8*>(kb + (size_t)k0c * CO_ + quad * 8);
            bf16x8 Bk1 = *reinterpret_cast<const bf16x8*>(kb + (size_t)k1c * CO_ + quad * 8);
            f32x4 S0 = __builtin_amdgcn_mfma_f32_16x16x32_bf16(Aq, Bk0, zf, 0, 0, 0);
            f32x4 S1 = __builtin_amdgcn_mfma_f32_16x16x32_bf16(Aq, Bk1, zf, 0, 0, 0);
            const bool v0 = k0 < HW_, v1 = k1 < HW_;
            #pragma unroll
            for (int r = 0; r < 4; ++r) {
                int row = w * 16 + quad * 4 + r;
                float p0v = v0 ? __expf(S0[r] * TEMP_ - mrw[r]) * lirw[r] : 0.f;
                float p1v = v1 ? __expf(S1[r] * TEMP_ - mrw[r]) * lirw[r] : 0.f;
                Pbuf[buf][row][l15]      = f2bf(p0v);
                Pbuf[buf][row][16 + l15] = f2bf(p1v);
            }
        }
        __syncthreads();

        // V B-fragments straight from global bf16 (lane: 8 contiguous keys)
        bf16x8 Bv[8];
        #pragma unroll
        for (int nt = 0; nt < 8; ++nt) {
            int c = c0 + nt * 16 + l15;
            Bv[nt] = *reinterpret_cast<const bf16x8*>(
                vb + (size_t)c * (T_ * HW_) + q0 + quad * 8);
        }
        #pragma unroll
        for (int mt = 0; mt < 4; ++mt) {
            bf16x8 Ap = *reinterpret_cast<const bf16x8*>(&Pbuf[buf][mt * 16 + l15][quad * 8]);
            #pragma unroll
            for (int nt = 0; nt < 8; ++nt)
                acc[mt][nt] = __builtin_amdgcn_mfma_f32_16x16x32_bf16(Ap, Bv[nt], acc[mt][nt], 0, 0, 0);
        }
        __syncthreads();
    }

    // epilogue: C-layout frag -> float4 stores (rows contiguous along reg)
    #pragma unroll
    for (int mt = 0; mt < 4; ++mt) {
        int pb = p0 + mt * 16;
        if (pb >= HW_) break;
        int prow = pb + quad * 4;
        #pragma unroll
        for (int nt = 0; nt < 8; ++nt) {
            int c = c0 + nt * 16 + l15;
            *reinterpret_cast<float4*>(outb + (size_t)c * (TT_ * HW_) + prow) =
                *reinterpret_cast<float4*>(&acc[mt][nt]);
        }
    }
}

// ---------------------------------------------------------------------------
// K3: gating. na = Wn . out_column, g = sigmoid(sum Watt*xa*na), scale column.
// grid: 392 * 256 = 100352 = B * 2T * HW. Boundary zeros stay zero.
// ---------------------------------------------------------------------------
__global__ __launch_bounds__(256) void gate_kernel(
    const float* __restrict__ Wn, const float* __restrict__ Watt,
    const float* __restrict__ xa, float* __restrict__ out)
{
    __shared__ float Wl[CO_ * C_];   // 64 KB
    const int tid = threadIdx.x;
    for (int i = tid; i < CO_ * C_; i += 256) Wl[i] = Wn[i];
    __syncthreads();

    const int gid = blockIdx.x * 256 + tid;     // [0, 100352)
    const int b = gid / (T2_ * HW_);
    const int r = gid % (T2_ * HW_);
    const int t2 = r / HW_;
    const int p = r % HW_;
    const int t = t2 >> 1, n = t2 & 1;
    const int tt = 3 * t + 2 * n;

    float* op = out + (size_t)b * C_ * TT_ * HW_ + (size_t)tt * HW_ + p;

    float na[CO_];
    #pragma unroll
    for (int o = 0; o < CO_; ++o) na[o] = 0.f;
    for (int c = 0; c < C_; ++c) {
        float v = op[(size_t)c * (TT_ * HW_)];
        #pragma unroll
        for (int o = 0; o < CO_; ++o) na[o] += Wl[o * C_ + c] * v;
    }

    const float* xab = xa + ((size_t)(b * T_ + t) * HW_ + p) * CO_;
    float g = 0.f;
    #pragma unroll
    for (int o = 0; o < CO_; ++o) g += Watt[o] * xab[o] * na[o];
    g = 1.f / (1.f + __expf(-g));

    for (int c = 0; c < C_; ++c) op[(size_t)c * (TT_ * HW_)] *= g;
}

extern "C" void kernel_launch(void* const* d_in, const int* in_sizes, int n_in,
                              void* d_out, int out_size, void* d_ws, size_t ws_size,
                              hipStream_t stream) {
    const float* x    = (const float*)d_in[0];
    const float* Ws   = (const float*)d_in[1];
    const float* Wx   = (const float*)d_in[2];
    const float* Wn   = (const float*)d_in[3];
    const float* Watt = (const float*)d_in[4];
    float* out = (float*)d_out;

    // ws layout: xnorm bf16 (3,211,264 B) | xa fp32 (6,422,528 B) | x bf16 (51,380,224 B)
    ushort* xnorm = (ushort*)d_ws;
    float*  xa    = (float*)((char*)d_ws + 3211264);
    ushort* xbf   = (ushort*)((char*)d_ws + 3211264 + 6422528);

    convert_kernel<<<dim3(12544), dim3(256), 0, stream>>>(
        (const float4*)x, (uint4*)xbf);
    proj_kernel<<<dim3(196), dim3(256), 0, stream>>>(x, Ws, out, xnorm, nullptr, 0);
    proj_kernel<<<dim3(196), dim3(256), 0, stream>>>(x, Wx, out, nullptr, xa, 1);
    attn_mfma<<<dim3(128 * PBLK), dim3(256), 0, stream>>>(xnorm, xbf, out);
    gate_kernel<<<dim3(392), dim3(256), 0, stream>>>(Wn, Watt, xa, out);
}